// Round 3
// baseline (2324.894 us; speedup 1.0000x reference)
//
#include <hip/hip_runtime.h>

#define NN 100000
#define NE 1200000
#define NG 512
#define NSEG (3 * NN)
#define CHUNK 1024
#define NCHUNK ((NSEG + CHUNK - 1) / CHUNK)

// ---- workspace layout (bytes), all 16B-aligned ----
static constexpr size_t AGG_OFF   = 0;                                  // 3*NN*64 f32
static constexpr size_t AGG_BYTES = (size_t)NSEG * 64 * 4;              // 76,800,000
static constexpr size_t CUR_OFF   = AGG_OFF + AGG_BYTES;                // NSEG ints (hist -> cursor)
static constexpr size_t START_OFF = CUR_OFF + (size_t)NSEG * 4;         // NSEG ints
static constexpr size_t CSUM_OFF  = START_OFF + (size_t)NSEG * 4;       // NCHUNK ints
static constexpr size_t ESRC_OFF  = CSUM_OFF + 4096;                    // NE ints
static constexpr size_t POOL_OFF  = ESRC_OFF + (size_t)NE * 4;          // NG*64 f32
static constexpr size_t H0_OFF    = POOL_OFF + (size_t)NG * 64 * 4;     // NN*32 f32
static constexpr size_t H1_OFF    = H0_OFF + (size_t)NN * 32 * 4;       // NN*64 f32
static constexpr size_t H2_OFF    = H1_OFF + (size_t)NN * 64 * 4;       // NN*64 f32

// ---- node embedding + pre MLP: h0[n][32] = relu(concat(se[x0],ce[x1]) @ pre_w + pre_b)
__global__ __launch_bounds__(256)
void k_embed_pre(const int* __restrict__ x, const float* __restrict__ se,
                 const float* __restrict__ ce, const float* __restrict__ pw,
                 const float* __restrict__ pb, float* __restrict__ h0) {
    __shared__ float sW[16 * 32];
    __shared__ float sB[32];
    for (int i = threadIdx.x; i < 512; i += blockDim.x) sW[i] = pw[i];
    if (threadIdx.x < 32) sB[threadIdx.x] = pb[threadIdx.x];
    __syncthreads();
    int n = blockIdx.x * blockDim.x + threadIdx.x;
    if (n >= NN) return;
    int si = x[2 * n], ci = x[2 * n + 1];
    float in[16];
#pragma unroll
    for (int k = 0; k < 8; k++) in[k] = se[si * 8 + k];
#pragma unroll
    for (int k = 0; k < 8; k++) in[8 + k] = ce[ci * 8 + k];
    float acc[32];
#pragma unroll
    for (int j = 0; j < 32; j++) acc[j] = sB[j];
#pragma unroll
    for (int k = 0; k < 16; k++) {
        float hv = in[k];
#pragma unroll
        for (int j = 0; j < 32; j++) acc[j] += hv * sW[k * 32 + j];
    }
    float* o = h0 + (size_t)n * 32;
#pragma unroll
    for (int j = 0; j < 32; j += 4) {
        float4 v = make_float4(fmaxf(acc[j], 0.f), fmaxf(acc[j + 1], 0.f),
                               fmaxf(acc[j + 2], 0.f), fmaxf(acc[j + 3], 0.f));
        *(float4*)(o + j) = v;
    }
}

// ---- histogram per (rel,dst) segment (into cur[], int atomics)
__global__ __launch_bounds__(256)
void k_count(const int* __restrict__ ei, const int* __restrict__ et, int* __restrict__ hist) {
    int e = blockIdx.x * blockDim.x + threadIdx.x;
    if (e >= NE) return;
    int d = ei[NE + e];
    int r = et[e];
    atomicAdd(&hist[r * NN + d], 1);
}

// ---- scan pass 1: per-chunk sums
__global__ __launch_bounds__(256)
void k_chunksum(const int* __restrict__ hist, int* __restrict__ csum) {
    __shared__ int s[256];
    int b = blockIdx.x, t = threadIdx.x;
    int base = b * CHUNK + t * 4;
    int sum = 0;
#pragma unroll
    for (int k = 0; k < 4; k++) {
        int i = base + k;
        if (i < NSEG) sum += hist[i];
    }
    s[t] = sum;
    __syncthreads();
    for (int off = 128; off > 0; off >>= 1) {
        if (t < off) s[t] += s[t + off];
        __syncthreads();
    }
    if (t == 0) csum[b] = s[0];
}

// ---- scan pass 2: exclusive scan of chunk sums (tiny, single thread)
__global__ void k_chunkscan(int* __restrict__ csum) {
    if (blockIdx.x == 0 && threadIdx.x == 0) {
        int run = 0;
        for (int i = 0; i < NCHUNK; i++) {
            int v = csum[i];
            csum[i] = run;
            run += v;
        }
    }
}

// ---- scan pass 3: local exclusive scan; writes start[] and re-inits cur[] (cursor)
__global__ __launch_bounds__(256)
void k_localscan(int* __restrict__ hist_cur, const int* __restrict__ csum,
                 int* __restrict__ start) {
    __shared__ int s[256];
    int b = blockIdx.x, t = threadIdx.x;
    int base = b * CHUNK + t * 4;
    int v[4];
    int s4 = 0;
#pragma unroll
    for (int k = 0; k < 4; k++) {
        int i = base + k;
        v[k] = (i < NSEG) ? hist_cur[i] : 0;
        s4 += v[k];
    }
    s[t] = s4;
    __syncthreads();
    for (int off = 1; off < 256; off <<= 1) {
        int x = (t >= off) ? s[t - off] : 0;
        __syncthreads();
        s[t] += x;
        __syncthreads();
    }
    int excl = s[t] - s4 + csum[b];
#pragma unroll
    for (int k = 0; k < 4; k++) {
        int i = base + k;
        if (i < NSEG) {
            start[i] = excl;
            hist_cur[i] = excl;  // cursor for fill
        }
        excl += v[k];
    }
}

// ---- fill CSR edge array (src ids), int-atomic cursors
__global__ __launch_bounds__(256)
void k_fill(const int* __restrict__ ei, const int* __restrict__ et,
            int* __restrict__ cur, int* __restrict__ esrc) {
    int e = blockIdx.x * blockDim.x + threadIdx.x;
    if (e >= NE) return;
    int s = ei[e], d = ei[NE + e], r = et[e];
    int pos = atomicAdd(&cur[r * NN + d], 1);
    esrc[pos] = s;
}

// ---- gather-aggregate: agg[seg][0:C] = sum_{edges in seg} h[src][0:C] (no atomics)
template <int C>
__global__ __launch_bounds__(256)
void k_gather(const int* __restrict__ start, const int* __restrict__ cur,
              const int* __restrict__ esrc, const float* __restrict__ h,
              float* __restrict__ agg) {
    constexpr int P = C / 4;
    int tid = blockIdx.x * blockDim.x + threadIdx.x;
    int seg = tid / P;
    int p = tid % P;
    if (seg >= NSEG) return;
    int st = start[seg], en = cur[seg];
    float4 acc = make_float4(0.f, 0.f, 0.f, 0.f);
    for (int i = st; i < en; i++) {
        int s = esrc[i];
        float4 v = *(const float4*)(h + (size_t)s * C + p * 4);
        acc.x += v.x; acc.y += v.y; acc.z += v.z; acc.w += v.w;
    }
    *(float4*)(agg + (size_t)seg * C + p * 4) = acc;
}

// ---- combine as tiled GEMM: out[NN][64] = relu(concat(h_in, agg_r/cnt_r) @ concat(root, W_r) + b)
// block = 128 nodes, 128 threads; thread = 8 nodes (stride 16) x 8 cols
template <int CIN>
__global__ __launch_bounds__(128, 2)
void k_combine_t(const float* __restrict__ h_in, const float* __restrict__ agg,
                 const int* __restrict__ start, const int* __restrict__ cur,
                 const float* __restrict__ root, const float* __restrict__ w,
                 const float* __restrict__ bias, float* __restrict__ h_out) {
    constexpr int BN = 128;
    constexpr int S = CIN + 4;            // row stride (floats): 16B-aligned, bank offset 4
    constexpr int F4R = CIN / 4;          // float4s per input row
    __shared__ float sIN[BN * S];
    __shared__ float sW[CIN * 64];

    const int tid = threadIdx.x;
    const int cg = tid & 7;               // col group -> cols 8*cg..8*cg+7
    const int ng = tid >> 3;              // 0..15; node rows ng + m*16
    const int n0 = blockIdx.x * BN;

    float4 acc0[8], acc1[8];
    const float4 b0 = *(const float4*)(bias + cg * 8);
    const float4 b1 = *(const float4*)(bias + cg * 8 + 4);
#pragma unroll
    for (int m = 0; m < 8; m++) { acc0[m] = b0; acc1[m] = b1; }

    for (int kb = 0; kb < 4; kb++) {
        const float* __restrict__ wsrc = (kb == 0) ? root : (w + (size_t)(kb - 1) * CIN * 64);
        // stage weights: CIN*64 floats = CIN*16 float4s
        for (int i = tid; i < CIN * 16; i += 128)
            *(float4*)(sW + (size_t)i * 4) = *(const float4*)(wsrc + (size_t)i * 4);
        // stage inputs (scaled by 1/cnt for rel chunks)
        {
            const int q = tid % F4R;
            const int r0 = tid / F4R;
            constexpr int RPP = 128 / F4R;
            for (int rr = r0; rr < BN; rr += RPP) {
                int n = n0 + rr;
                float4 v = make_float4(0.f, 0.f, 0.f, 0.f);
                if (n < NN) {
                    if (kb == 0) {
                        v = *(const float4*)(h_in + (size_t)n * CIN + q * 4);
                    } else {
                        int seg = (kb - 1) * NN + n;
                        float4 a = *(const float4*)(agg + (size_t)seg * CIN + q * 4);
                        int c = cur[seg] - start[seg];
                        float inv = 1.f / (float)(c > 1 ? c : 1);
                        v = make_float4(a.x * inv, a.y * inv, a.z * inv, a.w * inv);
                    }
                }
                *(float4*)(sIN + rr * S + q * 4) = v;
            }
        }
        __syncthreads();
        // compute
#pragma unroll
        for (int k = 0; k < CIN; k += 4) {
            float4 w0[4], w1[4];
#pragma unroll
            for (int i = 0; i < 4; i++) {
                w0[i] = *(const float4*)(sW + (k + i) * 64 + cg * 8);
                w1[i] = *(const float4*)(sW + (k + i) * 64 + cg * 8 + 4);
            }
#pragma unroll
            for (int m = 0; m < 8; m++) {
                float4 iv = *(const float4*)(sIN + (ng + m * 16) * S + k);
                acc0[m].x += iv.x * w0[0].x + iv.y * w0[1].x + iv.z * w0[2].x + iv.w * w0[3].x;
                acc0[m].y += iv.x * w0[0].y + iv.y * w0[1].y + iv.z * w0[2].y + iv.w * w0[3].y;
                acc0[m].z += iv.x * w0[0].z + iv.y * w0[1].z + iv.z * w0[2].z + iv.w * w0[3].z;
                acc0[m].w += iv.x * w0[0].w + iv.y * w0[1].w + iv.z * w0[2].w + iv.w * w0[3].w;
                acc1[m].x += iv.x * w1[0].x + iv.y * w1[1].x + iv.z * w1[2].x + iv.w * w1[3].x;
                acc1[m].y += iv.x * w1[0].y + iv.y * w1[1].y + iv.z * w1[2].y + iv.w * w1[3].y;
                acc1[m].z += iv.x * w1[0].z + iv.y * w1[1].z + iv.z * w1[2].z + iv.w * w1[3].z;
                acc1[m].w += iv.x * w1[0].w + iv.y * w1[1].w + iv.z * w1[2].w + iv.w * w1[3].w;
            }
        }
        if (kb < 3) __syncthreads();
    }
    // write out with relu
#pragma unroll
    for (int m = 0; m < 8; m++) {
        int n = n0 + ng + m * 16;
        if (n < NN) {
            float* o = h_out + (size_t)n * 64 + cg * 8;
            float4 r0 = make_float4(fmaxf(acc0[m].x, 0.f), fmaxf(acc0[m].y, 0.f),
                                    fmaxf(acc0[m].z, 0.f), fmaxf(acc0[m].w, 0.f));
            float4 r1 = make_float4(fmaxf(acc1[m].x, 0.f), fmaxf(acc1[m].y, 0.f),
                                    fmaxf(acc1[m].z, 0.f), fmaxf(acc1[m].w, 0.f));
            *(float4*)o = r0;
            *(float4*)(o + 4) = r1;
        }
    }
}

// ---- mean pool via binary search on sorted batch (no atomics); writes mean directly
__global__ __launch_bounds__(256)
void k_pool(const float* __restrict__ h, const int* __restrict__ batch,
            float* __restrict__ pool) {
    int g = blockIdx.x;
    auto lb = [&](int v) {
        int lo = 0, hi = NN;
        while (lo < hi) {
            int m = (lo + hi) >> 1;
            if (batch[m] < v) lo = m + 1; else hi = m;
        }
        return lo;
    };
    int st = lb(g), en = lb(g + 1);
    int col = threadIdx.x & 63, chunk = threadIdx.x >> 6;
    float acc = 0.f;
    for (int n = st + chunk; n < en; n += 4) acc += h[(size_t)n * 64 + col];
    __shared__ float s[256];
    s[threadIdx.x] = acc;
    __syncthreads();
    if (chunk == 0) {
        float tot = s[col] + s[64 + col] + s[128 + col] + s[192 + col];
        int c = en - st;
        pool[g * 64 + col] = tot / (float)(c > 1 ? c : 1);
    }
}

// ---- classifier: out[g][j] = cls_b[j] + pool[g] @ cls_w[:,j]   (pool already mean)
__global__ __launch_bounds__(256)
void k_final(const float* __restrict__ pool, const float* __restrict__ cw,
             const float* __restrict__ cb, float* __restrict__ out) {
    int t = blockIdx.x * blockDim.x + threadIdx.x;
    if (t >= NG * 10) return;
    int g = t / 10, j = t % 10;
    float acc = 0.f;
#pragma unroll
    for (int k = 0; k < 64; k++) acc += pool[g * 64 + k] * cw[k * 10 + j];
    out[t] = cb[j] + acc;
}

extern "C" void kernel_launch(void* const* d_in, const int* in_sizes, int n_in,
                              void* d_out, int out_size, void* d_ws, size_t ws_size,
                              hipStream_t stream) {
    const int* x      = (const int*)d_in[0];
    const int* ei     = (const int*)d_in[1];
    const int* et     = (const int*)d_in[2];
    const int* batch  = (const int*)d_in[3];
    const float* se   = (const float*)d_in[4];
    const float* ce   = (const float*)d_in[5];
    const float* pw   = (const float*)d_in[6];
    const float* pb   = (const float*)d_in[7];
    const float* w1   = (const float*)d_in[8];
    const float* root1= (const float*)d_in[9];
    const float* b1   = (const float*)d_in[10];
    const float* w2   = (const float*)d_in[11];
    const float* root2= (const float*)d_in[12];
    const float* b2   = (const float*)d_in[13];
    const float* cw   = (const float*)d_in[14];
    const float* cb   = (const float*)d_in[15];
    float* out = (float*)d_out;

    char* ws = (char*)d_ws;
    float* agg   = (float*)(ws + AGG_OFF);
    int*   cur   = (int*)(ws + CUR_OFF);     // histogram, then cursor (== segment end after fill)
    int*   start = (int*)(ws + START_OFF);
    int*   csum  = (int*)(ws + CSUM_OFF);
    int*   esrc  = (int*)(ws + ESRC_OFF);
    float* pool  = (float*)(ws + POOL_OFF);
    float* h0    = (float*)(ws + H0_OFF);
    float* h1    = (float*)(ws + H1_OFF);
    float* h2    = (float*)(ws + H2_OFF);

    // zero the histogram only
    hipMemsetAsync(cur, 0, (size_t)NSEG * 4, stream);

    k_embed_pre<<<(NN + 255) / 256, 256, 0, stream>>>(x, se, ce, pw, pb, h0);

    // CSR build
    k_count<<<(NE + 255) / 256, 256, 0, stream>>>(ei, et, cur);
    k_chunksum<<<NCHUNK, 256, 0, stream>>>(cur, csum);
    k_chunkscan<<<1, 64, 0, stream>>>(csum);
    k_localscan<<<NCHUNK, 256, 0, stream>>>(cur, csum, start);
    k_fill<<<(NE + 255) / 256, 256, 0, stream>>>(ei, et, cur, esrc);

    // layer 1
    k_gather<32><<<(NSEG * 8 + 255) / 256, 256, 0, stream>>>(start, cur, esrc, h0, agg);
    k_combine_t<32><<<(NN + 127) / 128, 128, 0, stream>>>(h0, agg, start, cur, root1, w1, b1, h1);

    // layer 2
    k_gather<64><<<(NSEG * 16 + 255) / 256, 256, 0, stream>>>(start, cur, esrc, h1, agg);
    k_combine_t<64><<<(NN + 127) / 128, 128, 0, stream>>>(h1, agg, start, cur, root2, w2, b2, h2);

    // pooling + classifier
    k_pool<<<NG, 256, 0, stream>>>(h2, batch, pool);
    k_final<<<(NG * 10 + 255) / 256, 256, 0, stream>>>(pool, cw, cb, out);
}

// Round 4
// 437.874 us; speedup vs baseline: 5.3095x; 5.3095x over previous
//
#include <hip/hip_runtime.h>

#define NN 100000
#define NE 1200000
#define NG 512
#define NSEG (3 * NN)
#define CHUNK 1024
#define NCHUNK ((NSEG + CHUNK - 1) / CHUNK)

// ---- workspace layout (bytes), all 16B-aligned ----
static constexpr size_t AGG_OFF   = 0;                                  // 3*NN*64 f32
static constexpr size_t AGG_BYTES = (size_t)NSEG * 64 * 4;              // 76,800,000
static constexpr size_t CUR_OFF   = AGG_OFF + AGG_BYTES;                // NSEG ints (hist -> cursor)
static constexpr size_t START_OFF = CUR_OFF + (size_t)NSEG * 4;         // NSEG ints
static constexpr size_t CSUM_OFF  = START_OFF + (size_t)NSEG * 4;       // NCHUNK ints
static constexpr size_t ESRC_OFF  = CSUM_OFF + 4096;                    // NE ints
static constexpr size_t POOL_OFF  = ESRC_OFF + (size_t)NE * 4;          // NG*64 f32
static constexpr size_t H0_OFF    = POOL_OFF + (size_t)NG * 64 * 4;     // NN*32 f32
static constexpr size_t H1_OFF    = H0_OFF + (size_t)NN * 32 * 4;       // NN*64 f32
static constexpr size_t H2_OFF    = H1_OFF + (size_t)NN * 64 * 4;       // NN*64 f32

// ---- node embedding + pre MLP: h0[n][32] = relu(concat(se[x0],ce[x1]) @ pre_w + pre_b)
__global__ __launch_bounds__(256)
void k_embed_pre(const int* __restrict__ x, const float* __restrict__ se,
                 const float* __restrict__ ce, const float* __restrict__ pw,
                 const float* __restrict__ pb, float* __restrict__ h0) {
    __shared__ float sW[16 * 32];
    __shared__ float sB[32];
    for (int i = threadIdx.x; i < 512; i += blockDim.x) sW[i] = pw[i];
    if (threadIdx.x < 32) sB[threadIdx.x] = pb[threadIdx.x];
    __syncthreads();
    int n = blockIdx.x * blockDim.x + threadIdx.x;
    if (n >= NN) return;
    int si = x[2 * n], ci = x[2 * n + 1];
    float in[16];
#pragma unroll
    for (int k = 0; k < 8; k++) in[k] = se[si * 8 + k];
#pragma unroll
    for (int k = 0; k < 8; k++) in[8 + k] = ce[ci * 8 + k];
    float acc[32];
#pragma unroll
    for (int j = 0; j < 32; j++) acc[j] = sB[j];
#pragma unroll
    for (int k = 0; k < 16; k++) {
        float hv = in[k];
#pragma unroll
        for (int j = 0; j < 32; j++) acc[j] += hv * sW[k * 32 + j];
    }
    float* o = h0 + (size_t)n * 32;
#pragma unroll
    for (int j = 0; j < 32; j += 4) {
        float4 v = make_float4(fmaxf(acc[j], 0.f), fmaxf(acc[j + 1], 0.f),
                               fmaxf(acc[j + 2], 0.f), fmaxf(acc[j + 3], 0.f));
        *(float4*)(o + j) = v;
    }
}

// ---- histogram per (rel,dst) segment (into cur[], int atomics)
__global__ __launch_bounds__(256)
void k_count(const int* __restrict__ ei, const int* __restrict__ et, int* __restrict__ hist) {
    int e = blockIdx.x * blockDim.x + threadIdx.x;
    if (e >= NE) return;
    int d = ei[NE + e];
    int r = et[e];
    atomicAdd(&hist[r * NN + d], 1);
}

// ---- scan pass 1: per-chunk sums
__global__ __launch_bounds__(256)
void k_chunksum(const int* __restrict__ hist, int* __restrict__ csum) {
    __shared__ int s[256];
    int b = blockIdx.x, t = threadIdx.x;
    int base = b * CHUNK + t * 4;
    int sum = 0;
#pragma unroll
    for (int k = 0; k < 4; k++) {
        int i = base + k;
        if (i < NSEG) sum += hist[i];
    }
    s[t] = sum;
    __syncthreads();
    for (int off = 128; off > 0; off >>= 1) {
        if (t < off) s[t] += s[t + off];
        __syncthreads();
    }
    if (t == 0) csum[b] = s[0];
}

// ---- scan pass 2: exclusive scan of chunk sums (tiny, single thread)
__global__ void k_chunkscan(int* __restrict__ csum) {
    if (blockIdx.x == 0 && threadIdx.x == 0) {
        int run = 0;
        for (int i = 0; i < NCHUNK; i++) {
            int v = csum[i];
            csum[i] = run;
            run += v;
        }
    }
}

// ---- scan pass 3: local exclusive scan; writes start[] and re-inits cur[] (cursor)
__global__ __launch_bounds__(256)
void k_localscan(int* __restrict__ hist_cur, const int* __restrict__ csum,
                 int* __restrict__ start) {
    __shared__ int s[256];
    int b = blockIdx.x, t = threadIdx.x;
    int base = b * CHUNK + t * 4;
    int v[4];
    int s4 = 0;
#pragma unroll
    for (int k = 0; k < 4; k++) {
        int i = base + k;
        v[k] = (i < NSEG) ? hist_cur[i] : 0;
        s4 += v[k];
    }
    s[t] = s4;
    __syncthreads();
    for (int off = 1; off < 256; off <<= 1) {
        int x = (t >= off) ? s[t - off] : 0;
        __syncthreads();
        s[t] += x;
        __syncthreads();
    }
    int excl = s[t] - s4 + csum[b];
#pragma unroll
    for (int k = 0; k < 4; k++) {
        int i = base + k;
        if (i < NSEG) {
            start[i] = excl;
            hist_cur[i] = excl;  // cursor for fill
        }
        excl += v[k];
    }
}

// ---- fill CSR edge array (src ids), int-atomic cursors
__global__ __launch_bounds__(256)
void k_fill(const int* __restrict__ ei, const int* __restrict__ et,
            int* __restrict__ cur, int* __restrict__ esrc) {
    int e = blockIdx.x * blockDim.x + threadIdx.x;
    if (e >= NE) return;
    int s = ei[e], d = ei[NE + e], r = et[e];
    int pos = atomicAdd(&cur[r * NN + d], 1);
    esrc[pos] = s;
}

// ---- gather-aggregate: agg[seg][0:C] = MEAN_{edges in seg} h[src][0:C] (no atomics)
template <int C>
__global__ __launch_bounds__(256)
void k_gather(const int* __restrict__ start, const int* __restrict__ cur,
              const int* __restrict__ esrc, const float* __restrict__ h,
              float* __restrict__ agg) {
    constexpr int P = C / 4;
    int tid = blockIdx.x * blockDim.x + threadIdx.x;
    int seg = tid / P;
    int p = tid % P;
    if (seg >= NSEG) return;
    int st = start[seg], en = cur[seg];
    float4 acc = make_float4(0.f, 0.f, 0.f, 0.f);
    for (int i = st; i < en; i++) {
        int s = esrc[i];
        float4 v = *(const float4*)(h + (size_t)s * C + p * 4);
        acc.x += v.x; acc.y += v.y; acc.z += v.z; acc.w += v.w;
    }
    int c = en - st;
    float inv = 1.f / (float)(c > 1 ? c : 1);
    acc.x *= inv; acc.y *= inv; acc.z *= inv; acc.w *= inv;
    *(float4*)(agg + (size_t)seg * C + p * 4) = acc;
}

// ---- combine as tiled GEMM: out[NN][64] = relu(concat(h_in, mean_r) @ concat(root, W_r) + b)
// block = 256 threads, 128 nodes; thread = 4 nodes (stride 32) x 8 cols -> 32 acc VGPRs
template <int CIN>
__global__ __launch_bounds__(256, 1)
void k_combine_t(const float* __restrict__ h_in, const float* __restrict__ agg,
                 const float* __restrict__ root, const float* __restrict__ w,
                 const float* __restrict__ bias, float* __restrict__ h_out) {
    constexpr int BN = 128;
    constexpr int S = CIN + 4;            // row stride (floats): 16B-aligned, spreads banks
    constexpr int F4R = CIN / 4;          // float4s per input row
    __shared__ float sIN[BN * S];
    __shared__ float sW[CIN * 64];

    const int tid = threadIdx.x;
    const int cg = tid & 7;               // col group -> cols 8*cg..8*cg+7
    const int ng = tid >> 3;              // 0..31; node rows ng + m*32
    const int n0 = blockIdx.x * BN;

    float4 acc[4][2];
    {
        const float4 b0 = *(const float4*)(bias + cg * 8);
        const float4 b1 = *(const float4*)(bias + cg * 8 + 4);
#pragma unroll
        for (int m = 0; m < 4; m++) { acc[m][0] = b0; acc[m][1] = b1; }
    }

    for (int kb = 0; kb < 4; kb++) {
        const float* __restrict__ wsrc = (kb == 0) ? root : (w + (size_t)(kb - 1) * CIN * 64);
        const float* __restrict__ isrc = (kb == 0) ? h_in : (agg + (size_t)(kb - 1) * NN * CIN);
        // stage weights: CIN*16 float4s
        for (int i = tid; i < CIN * 16; i += 256)
            *(float4*)(sW + (size_t)i * 4) = *(const float4*)(wsrc + (size_t)i * 4);
        // stage inputs
        {
            const int q = tid % F4R;
            const int r0 = tid / F4R;
            constexpr int RPP = 256 / F4R;
            for (int rr = r0; rr < BN; rr += RPP) {
                int n = n0 + rr;
                float4 v = make_float4(0.f, 0.f, 0.f, 0.f);
                if (n < NN) v = *(const float4*)(isrc + (size_t)n * CIN + q * 4);
                *(float4*)(sIN + rr * S + q * 4) = v;
            }
        }
        __syncthreads();
#pragma unroll 2
        for (int k = 0; k < CIN; k += 4) {
            float4 w0[4], w1[4];
#pragma unroll
            for (int i = 0; i < 4; i++) {
                w0[i] = *(const float4*)(sW + (k + i) * 64 + cg * 8);
                w1[i] = *(const float4*)(sW + (k + i) * 64 + cg * 8 + 4);
            }
#pragma unroll
            for (int m = 0; m < 4; m++) {
                float4 iv = *(const float4*)(sIN + (ng + m * 32) * S + k);
                acc[m][0].x += iv.x * w0[0].x + iv.y * w0[1].x + iv.z * w0[2].x + iv.w * w0[3].x;
                acc[m][0].y += iv.x * w0[0].y + iv.y * w0[1].y + iv.z * w0[2].y + iv.w * w0[3].y;
                acc[m][0].z += iv.x * w0[0].z + iv.y * w0[1].z + iv.z * w0[2].z + iv.w * w0[3].z;
                acc[m][0].w += iv.x * w0[0].w + iv.y * w0[1].w + iv.z * w0[2].w + iv.w * w0[3].w;
                acc[m][1].x += iv.x * w1[0].x + iv.y * w1[1].x + iv.z * w1[2].x + iv.w * w1[3].x;
                acc[m][1].y += iv.x * w1[0].y + iv.y * w1[1].y + iv.z * w1[2].y + iv.w * w1[3].y;
                acc[m][1].z += iv.x * w1[0].z + iv.y * w1[1].z + iv.z * w1[2].z + iv.w * w1[3].z;
                acc[m][1].w += iv.x * w1[0].w + iv.y * w1[1].w + iv.z * w1[2].w + iv.w * w1[3].w;
            }
        }
        if (kb < 3) __syncthreads();
    }
    // write out with relu
#pragma unroll
    for (int m = 0; m < 4; m++) {
        int n = n0 + ng + m * 32;
        if (n < NN) {
            float* o = h_out + (size_t)n * 64 + cg * 8;
            float4 r0 = make_float4(fmaxf(acc[m][0].x, 0.f), fmaxf(acc[m][0].y, 0.f),
                                    fmaxf(acc[m][0].z, 0.f), fmaxf(acc[m][0].w, 0.f));
            float4 r1 = make_float4(fmaxf(acc[m][1].x, 0.f), fmaxf(acc[m][1].y, 0.f),
                                    fmaxf(acc[m][1].z, 0.f), fmaxf(acc[m][1].w, 0.f));
            *(float4*)o = r0;
            *(float4*)(o + 4) = r1;
        }
    }
}

// ---- mean pool via binary search on sorted batch (no atomics); writes mean directly
__global__ __launch_bounds__(256)
void k_pool(const float* __restrict__ h, const int* __restrict__ batch,
            float* __restrict__ pool) {
    int g = blockIdx.x;
    auto lb = [&](int v) {
        int lo = 0, hi = NN;
        while (lo < hi) {
            int m = (lo + hi) >> 1;
            if (batch[m] < v) lo = m + 1; else hi = m;
        }
        return lo;
    };
    int st = lb(g), en = lb(g + 1);
    int col = threadIdx.x & 63, chunk = threadIdx.x >> 6;
    float acc = 0.f;
    for (int n = st + chunk; n < en; n += 4) acc += h[(size_t)n * 64 + col];
    __shared__ float s[256];
    s[threadIdx.x] = acc;
    __syncthreads();
    if (chunk == 0) {
        float tot = s[col] + s[64 + col] + s[128 + col] + s[192 + col];
        int c = en - st;
        pool[g * 64 + col] = tot / (float)(c > 1 ? c : 1);
    }
}

// ---- classifier: out[g][j] = cls_b[j] + pool[g] @ cls_w[:,j]   (pool already mean)
__global__ __launch_bounds__(256)
void k_final(const float* __restrict__ pool, const float* __restrict__ cw,
             const float* __restrict__ cb, float* __restrict__ out) {
    int t = blockIdx.x * blockDim.x + threadIdx.x;
    if (t >= NG * 10) return;
    int g = t / 10, j = t % 10;
    float acc = 0.f;
#pragma unroll
    for (int k = 0; k < 64; k++) acc += pool[g * 64 + k] * cw[k * 10 + j];
    out[t] = cb[j] + acc;
}

extern "C" void kernel_launch(void* const* d_in, const int* in_sizes, int n_in,
                              void* d_out, int out_size, void* d_ws, size_t ws_size,
                              hipStream_t stream) {
    const int* x      = (const int*)d_in[0];
    const int* ei     = (const int*)d_in[1];
    const int* et     = (const int*)d_in[2];
    const int* batch  = (const int*)d_in[3];
    const float* se   = (const float*)d_in[4];
    const float* ce   = (const float*)d_in[5];
    const float* pw   = (const float*)d_in[6];
    const float* pb   = (const float*)d_in[7];
    const float* w1   = (const float*)d_in[8];
    const float* root1= (const float*)d_in[9];
    const float* b1   = (const float*)d_in[10];
    const float* w2   = (const float*)d_in[11];
    const float* root2= (const float*)d_in[12];
    const float* b2   = (const float*)d_in[13];
    const float* cw   = (const float*)d_in[14];
    const float* cb   = (const float*)d_in[15];
    float* out = (float*)d_out;

    char* ws = (char*)d_ws;
    float* agg   = (float*)(ws + AGG_OFF);
    int*   cur   = (int*)(ws + CUR_OFF);     // histogram, then cursor (== segment end after fill)
    int*   start = (int*)(ws + START_OFF);
    int*   csum  = (int*)(ws + CSUM_OFF);
    int*   esrc  = (int*)(ws + ESRC_OFF);
    float* pool  = (float*)(ws + POOL_OFF);
    float* h0    = (float*)(ws + H0_OFF);
    float* h1    = (float*)(ws + H1_OFF);
    float* h2    = (float*)(ws + H2_OFF);

    // zero the histogram only
    hipMemsetAsync(cur, 0, (size_t)NSEG * 4, stream);

    k_embed_pre<<<(NN + 255) / 256, 256, 0, stream>>>(x, se, ce, pw, pb, h0);

    // CSR build
    k_count<<<(NE + 255) / 256, 256, 0, stream>>>(ei, et, cur);
    k_chunksum<<<NCHUNK, 256, 0, stream>>>(cur, csum);
    k_chunkscan<<<1, 64, 0, stream>>>(csum);
    k_localscan<<<NCHUNK, 256, 0, stream>>>(cur, csum, start);
    k_fill<<<(NE + 255) / 256, 256, 0, stream>>>(ei, et, cur, esrc);

    // layer 1
    k_gather<32><<<(NSEG * 8 + 255) / 256, 256, 0, stream>>>(start, cur, esrc, h0, agg);
    k_combine_t<32><<<(NN + 127) / 128, 256, 0, stream>>>(h0, agg, root1, w1, b1, h1);

    // layer 2
    k_gather<64><<<(NSEG * 16 + 255) / 256, 256, 0, stream>>>(start, cur, esrc, h1, agg);
    k_combine_t<64><<<(NN + 127) / 128, 256, 0, stream>>>(h1, agg, root2, w2, b2, h2);

    // pooling + classifier
    k_pool<<<NG, 256, 0, stream>>>(h2, batch, pool);
    k_final<<<(NG * 10 + 255) / 256, 256, 0, stream>>>(pool, cw, cb, out);
}

// Round 5
// 416.116 us; speedup vs baseline: 5.5871x; 1.0523x over previous
//
#include <hip/hip_runtime.h>

#define NN 100000
#define NE 1200000
#define NG 512
#define NSEG (3 * NN)
#define CHUNK 1024
#define NCHUNK ((NSEG + CHUNK - 1) / CHUNK)

// ---- workspace layout (bytes), all 16B-aligned ----
static constexpr size_t AGG_OFF   = 0;                                  // 3*NN*64 f32
static constexpr size_t AGG_BYTES = (size_t)NSEG * 64 * 4;              // 76,800,000
static constexpr size_t CUR_OFF   = AGG_OFF + AGG_BYTES;                // NSEG ints (hist -> cursor)
static constexpr size_t START_OFF = CUR_OFF + (size_t)NSEG * 4;         // NSEG ints
static constexpr size_t CSUM_OFF  = START_OFF + (size_t)NSEG * 4;       // NCHUNK ints
static constexpr size_t ESRC_OFF  = CSUM_OFF + 4096;                    // NE ints
static constexpr size_t POOL_OFF  = ESRC_OFF + (size_t)NE * 4;          // NG*64 f32
static constexpr size_t H0_OFF    = POOL_OFF + (size_t)NG * 64 * 4;     // NN*32 f32
static constexpr size_t H1_OFF    = H0_OFF + (size_t)NN * 32 * 4;       // NN*64 f32
static constexpr size_t H2_OFF    = H1_OFF + (size_t)NN * 64 * 4;       // NN*64 f32

// ---- node embedding + pre MLP: h0[n][32] = relu(concat(se[x0],ce[x1]) @ pre_w + pre_b)
__global__ __launch_bounds__(256)
void k_embed_pre(const int* __restrict__ x, const float* __restrict__ se,
                 const float* __restrict__ ce, const float* __restrict__ pw,
                 const float* __restrict__ pb, float* __restrict__ h0) {
    __shared__ float sW[16 * 32];
    __shared__ float sB[32];
    for (int i = threadIdx.x; i < 512; i += blockDim.x) sW[i] = pw[i];
    if (threadIdx.x < 32) sB[threadIdx.x] = pb[threadIdx.x];
    __syncthreads();
    int n = blockIdx.x * blockDim.x + threadIdx.x;
    if (n >= NN) return;
    int si = x[2 * n], ci = x[2 * n + 1];
    float in[16];
#pragma unroll
    for (int k = 0; k < 8; k++) in[k] = se[si * 8 + k];
#pragma unroll
    for (int k = 0; k < 8; k++) in[8 + k] = ce[ci * 8 + k];
    float acc[32];
#pragma unroll
    for (int j = 0; j < 32; j++) acc[j] = sB[j];
#pragma unroll
    for (int k = 0; k < 16; k++) {
        float hv = in[k];
#pragma unroll
        for (int j = 0; j < 32; j++) acc[j] += hv * sW[k * 32 + j];
    }
    float* o = h0 + (size_t)n * 32;
#pragma unroll
    for (int j = 0; j < 32; j += 4) {
        float4 v = make_float4(fmaxf(acc[j], 0.f), fmaxf(acc[j + 1], 0.f),
                               fmaxf(acc[j + 2], 0.f), fmaxf(acc[j + 3], 0.f));
        *(float4*)(o + j) = v;
    }
}

// ---- histogram per (rel,dst) segment (into cur[], int atomics)
__global__ __launch_bounds__(256)
void k_count(const int* __restrict__ ei, const int* __restrict__ et, int* __restrict__ hist) {
    int e = blockIdx.x * blockDim.x + threadIdx.x;
    if (e >= NE) return;
    int d = ei[NE + e];
    int r = et[e];
    atomicAdd(&hist[r * NN + d], 1);
}

// ---- scan pass 1: per-chunk sums
__global__ __launch_bounds__(256)
void k_chunksum(const int* __restrict__ hist, int* __restrict__ csum) {
    __shared__ int s[256];
    int b = blockIdx.x, t = threadIdx.x;
    int base = b * CHUNK + t * 4;
    int sum = 0;
#pragma unroll
    for (int k = 0; k < 4; k++) {
        int i = base + k;
        if (i < NSEG) sum += hist[i];
    }
    s[t] = sum;
    __syncthreads();
    for (int off = 128; off > 0; off >>= 1) {
        if (t < off) s[t] += s[t + off];
        __syncthreads();
    }
    if (t == 0) csum[b] = s[0];
}

// ---- scan pass 2: exclusive scan of chunk sums (one 512-thread block)
__global__ __launch_bounds__(512)
void k_chunkscan(int* __restrict__ csum) {
    __shared__ int s[512];
    int t = threadIdx.x;
    int v = (t < NCHUNK) ? csum[t] : 0;
    s[t] = v;
    __syncthreads();
    for (int off = 1; off < 512; off <<= 1) {
        int x = (t >= off) ? s[t - off] : 0;
        __syncthreads();
        s[t] += x;
        __syncthreads();
    }
    if (t < NCHUNK) csum[t] = s[t] - v;   // exclusive
}

// ---- scan pass 3: local exclusive scan; writes start[] and re-inits cur[] (cursor)
__global__ __launch_bounds__(256)
void k_localscan(int* __restrict__ hist_cur, const int* __restrict__ csum,
                 int* __restrict__ start) {
    __shared__ int s[256];
    int b = blockIdx.x, t = threadIdx.x;
    int base = b * CHUNK + t * 4;
    int v[4];
    int s4 = 0;
#pragma unroll
    for (int k = 0; k < 4; k++) {
        int i = base + k;
        v[k] = (i < NSEG) ? hist_cur[i] : 0;
        s4 += v[k];
    }
    s[t] = s4;
    __syncthreads();
    for (int off = 1; off < 256; off <<= 1) {
        int x = (t >= off) ? s[t - off] : 0;
        __syncthreads();
        s[t] += x;
        __syncthreads();
    }
    int excl = s[t] - s4 + csum[b];
#pragma unroll
    for (int k = 0; k < 4; k++) {
        int i = base + k;
        if (i < NSEG) {
            start[i] = excl;
            hist_cur[i] = excl;  // cursor for fill
        }
        excl += v[k];
    }
}

// ---- fill CSR edge array (src ids), int-atomic cursors
__global__ __launch_bounds__(256)
void k_fill(const int* __restrict__ ei, const int* __restrict__ et,
            int* __restrict__ cur, int* __restrict__ esrc) {
    int e = blockIdx.x * blockDim.x + threadIdx.x;
    if (e >= NE) return;
    int s = ei[e], d = ei[NE + e], r = et[e];
    int pos = atomicAdd(&cur[r * NN + d], 1);
    esrc[pos] = s;
}

// ---- gather-aggregate: agg[seg][0:C] = MEAN_{edges in seg} h[src][0:C]
// unroll-4 over edges for memory-level parallelism
template <int C>
__global__ __launch_bounds__(256)
void k_gather(const int* __restrict__ start, const int* __restrict__ cur,
              const int* __restrict__ esrc, const float* __restrict__ h,
              float* __restrict__ agg) {
    constexpr int P = C / 4;
    int tid = blockIdx.x * blockDim.x + threadIdx.x;
    int seg = tid / P;
    int p = tid % P;
    if (seg >= NSEG) return;
    int st = start[seg], en = cur[seg];
    float4 acc = make_float4(0.f, 0.f, 0.f, 0.f);
    int i = st;
    for (; i + 4 <= en; i += 4) {
        int s0 = esrc[i + 0], s1 = esrc[i + 1], s2 = esrc[i + 2], s3 = esrc[i + 3];
        float4 v0 = *(const float4*)(h + (size_t)s0 * C + p * 4);
        float4 v1 = *(const float4*)(h + (size_t)s1 * C + p * 4);
        float4 v2 = *(const float4*)(h + (size_t)s2 * C + p * 4);
        float4 v3 = *(const float4*)(h + (size_t)s3 * C + p * 4);
        acc.x += (v0.x + v1.x) + (v2.x + v3.x);
        acc.y += (v0.y + v1.y) + (v2.y + v3.y);
        acc.z += (v0.z + v1.z) + (v2.z + v3.z);
        acc.w += (v0.w + v1.w) + (v2.w + v3.w);
    }
    for (; i < en; i++) {
        int s = esrc[i];
        float4 v = *(const float4*)(h + (size_t)s * C + p * 4);
        acc.x += v.x; acc.y += v.y; acc.z += v.z; acc.w += v.w;
    }
    int c = en - st;
    float inv = 1.f / (float)(c > 1 ? c : 1);
    acc.x *= inv; acc.y *= inv; acc.z *= inv; acc.w *= inv;
    *(float4*)(agg + (size_t)seg * C + p * 4) = acc;
}

// ---- combine as tiled GEMM with async-stage pipeline (T14):
// out[NN][64] = relu(concat(h_in, mean_r) @ concat(root, W_r) + b)
// block = 256 threads, 128 nodes; thread = 4 nodes (stride 32) x 8 cols
template <int CIN>
__global__ __launch_bounds__(256, 1)
void k_combine_t(const float* __restrict__ h_in, const float* __restrict__ agg,
                 const float* __restrict__ root, const float* __restrict__ w,
                 const float* __restrict__ bias, float* __restrict__ h_out) {
    constexpr int BN = 128;
    constexpr int S = CIN + 4;            // row stride (floats)
    constexpr int F4R = CIN / 4;          // float4s per input row
    constexpr int NWT = CIN * 16 / 256;   // weight float4 loads per thread (2 or 4)
    constexpr int RPP = 256 / F4R;        // rows staged per pass
    constexpr int NIT = BN / RPP;         // input float4 loads per thread (4 or 8)
    __shared__ float sIN[BN * S];
    __shared__ float sW[CIN * 64];

    const int tid = threadIdx.x;
    const int cg = tid & 7;               // col group -> cols 8*cg..8*cg+7
    const int ng = tid >> 3;              // 0..31; node rows ng + m*32
    const int n0 = blockIdx.x * BN;
    const int q = tid % F4R;
    const int r0 = tid / F4R;

    float4 rW[NWT], rI[NIT];

    auto load_stage = [&](int kb) {
        const float* __restrict__ wsrc = (kb == 0) ? root : (w + (size_t)(kb - 1) * CIN * 64);
        const float* __restrict__ isrc = (kb == 0) ? h_in : (agg + (size_t)(kb - 1) * NN * CIN);
#pragma unroll
        for (int i = 0; i < NWT; i++)
            rW[i] = *(const float4*)(wsrc + (size_t)(tid + i * 256) * 4);
#pragma unroll
        for (int it = 0; it < NIT; it++) {
            int n = n0 + r0 + it * RPP;
            rI[it] = (n < NN) ? *(const float4*)(isrc + (size_t)n * CIN + q * 4)
                              : make_float4(0.f, 0.f, 0.f, 0.f);
        }
    };

    float4 acc[4][2];
    {
        const float4 b0 = *(const float4*)(bias + cg * 8);
        const float4 b1 = *(const float4*)(bias + cg * 8 + 4);
#pragma unroll
        for (int m = 0; m < 4; m++) { acc[m][0] = b0; acc[m][1] = b1; }
    }

    load_stage(0);
    for (int kb = 0; kb < 4; kb++) {
        // write staged regs to LDS
#pragma unroll
        for (int i = 0; i < NWT; i++)
            *(float4*)(sW + (size_t)(tid + i * 256) * 4) = rW[i];
#pragma unroll
        for (int it = 0; it < NIT; it++)
            *(float4*)(sIN + (r0 + it * RPP) * S + q * 4) = rI[it];
        __syncthreads();
        // issue next chunk's global loads; latency hides under compute below
        if (kb < 3) load_stage(kb + 1);
        // compute
#pragma unroll 2
        for (int k = 0; k < CIN; k += 4) {
            float4 w0[4], w1[4];
#pragma unroll
            for (int i = 0; i < 4; i++) {
                w0[i] = *(const float4*)(sW + (k + i) * 64 + cg * 8);
                w1[i] = *(const float4*)(sW + (k + i) * 64 + cg * 8 + 4);
            }
#pragma unroll
            for (int m = 0; m < 4; m++) {
                float4 iv = *(const float4*)(sIN + (ng + m * 32) * S + k);
                acc[m][0].x += iv.x * w0[0].x + iv.y * w0[1].x + iv.z * w0[2].x + iv.w * w0[3].x;
                acc[m][0].y += iv.x * w0[0].y + iv.y * w0[1].y + iv.z * w0[2].y + iv.w * w0[3].y;
                acc[m][0].z += iv.x * w0[0].z + iv.y * w0[1].z + iv.z * w0[2].z + iv.w * w0[3].z;
                acc[m][0].w += iv.x * w0[0].w + iv.y * w0[1].w + iv.z * w0[2].w + iv.w * w0[3].w;
                acc[m][1].x += iv.x * w1[0].x + iv.y * w1[1].x + iv.z * w1[2].x + iv.w * w1[3].x;
                acc[m][1].y += iv.x * w1[0].y + iv.y * w1[1].y + iv.z * w1[2].y + iv.w * w1[3].y;
                acc[m][1].z += iv.x * w1[0].z + iv.y * w1[1].z + iv.z * w1[2].z + iv.w * w1[3].z;
                acc[m][1].w += iv.x * w1[0].w + iv.y * w1[1].w + iv.z * w1[2].w + iv.w * w1[3].w;
            }
        }
        if (kb < 3) __syncthreads();
    }
    // write out with relu
#pragma unroll
    for (int m = 0; m < 4; m++) {
        int n = n0 + ng + m * 32;
        if (n < NN) {
            float* o = h_out + (size_t)n * 64 + cg * 8;
            float4 r0v = make_float4(fmaxf(acc[m][0].x, 0.f), fmaxf(acc[m][0].y, 0.f),
                                     fmaxf(acc[m][0].z, 0.f), fmaxf(acc[m][0].w, 0.f));
            float4 r1v = make_float4(fmaxf(acc[m][1].x, 0.f), fmaxf(acc[m][1].y, 0.f),
                                     fmaxf(acc[m][1].z, 0.f), fmaxf(acc[m][1].w, 0.f));
            *(float4*)o = r0v;
            *(float4*)(o + 4) = r1v;
        }
    }
}

// ---- mean pool via binary search on sorted batch (no atomics); writes mean directly
__global__ __launch_bounds__(256)
void k_pool(const float* __restrict__ h, const int* __restrict__ batch,
            float* __restrict__ pool) {
    int g = blockIdx.x;
    auto lb = [&](int v) {
        int lo = 0, hi = NN;
        while (lo < hi) {
            int m = (lo + hi) >> 1;
            if (batch[m] < v) lo = m + 1; else hi = m;
        }
        return lo;
    };
    int st = lb(g), en = lb(g + 1);
    int col = threadIdx.x & 63, chunk = threadIdx.x >> 6;
    float acc = 0.f;
    for (int n = st + chunk; n < en; n += 4) acc += h[(size_t)n * 64 + col];
    __shared__ float s[256];
    s[threadIdx.x] = acc;
    __syncthreads();
    if (chunk == 0) {
        float tot = s[col] + s[64 + col] + s[128 + col] + s[192 + col];
        int c = en - st;
        pool[g * 64 + col] = tot / (float)(c > 1 ? c : 1);
    }
}

// ---- classifier: out[g][j] = cls_b[j] + pool[g] @ cls_w[:,j]   (pool already mean)
__global__ __launch_bounds__(256)
void k_final(const float* __restrict__ pool, const float* __restrict__ cw,
             const float* __restrict__ cb, float* __restrict__ out) {
    int t = blockIdx.x * blockDim.x + threadIdx.x;
    if (t >= NG * 10) return;
    int g = t / 10, j = t % 10;
    float acc = 0.f;
#pragma unroll
    for (int k = 0; k < 64; k++) acc += pool[g * 64 + k] * cw[k * 10 + j];
    out[t] = cb[j] + acc;
}

extern "C" void kernel_launch(void* const* d_in, const int* in_sizes, int n_in,
                              void* d_out, int out_size, void* d_ws, size_t ws_size,
                              hipStream_t stream) {
    const int* x      = (const int*)d_in[0];
    const int* ei     = (const int*)d_in[1];
    const int* et     = (const int*)d_in[2];
    const int* batch  = (const int*)d_in[3];
    const float* se   = (const float*)d_in[4];
    const float* ce   = (const float*)d_in[5];
    const float* pw   = (const float*)d_in[6];
    const float* pb   = (const float*)d_in[7];
    const float* w1   = (const float*)d_in[8];
    const float* root1= (const float*)d_in[9];
    const float* b1   = (const float*)d_in[10];
    const float* w2   = (const float*)d_in[11];
    const float* root2= (const float*)d_in[12];
    const float* b2   = (const float*)d_in[13];
    const float* cw   = (const float*)d_in[14];
    const float* cb   = (const float*)d_in[15];
    float* out = (float*)d_out;

    char* ws = (char*)d_ws;
    float* agg   = (float*)(ws + AGG_OFF);
    int*   cur   = (int*)(ws + CUR_OFF);     // histogram, then cursor (== segment end after fill)
    int*   start = (int*)(ws + START_OFF);
    int*   csum  = (int*)(ws + CSUM_OFF);
    int*   esrc  = (int*)(ws + ESRC_OFF);
    float* pool  = (float*)(ws + POOL_OFF);
    float* h0    = (float*)(ws + H0_OFF);
    float* h1    = (float*)(ws + H1_OFF);
    float* h2    = (float*)(ws + H2_OFF);

    // zero the histogram only
    hipMemsetAsync(cur, 0, (size_t)NSEG * 4, stream);

    k_embed_pre<<<(NN + 255) / 256, 256, 0, stream>>>(x, se, ce, pw, pb, h0);

    // CSR build
    k_count<<<(NE + 255) / 256, 256, 0, stream>>>(ei, et, cur);
    k_chunksum<<<NCHUNK, 256, 0, stream>>>(cur, csum);
    k_chunkscan<<<1, 512, 0, stream>>>(csum);
    k_localscan<<<NCHUNK, 256, 0, stream>>>(cur, csum, start);
    k_fill<<<(NE + 255) / 256, 256, 0, stream>>>(ei, et, cur, esrc);

    // layer 1
    k_gather<32><<<(NSEG * 8 + 255) / 256, 256, 0, stream>>>(start, cur, esrc, h0, agg);
    k_combine_t<32><<<(NN + 127) / 128, 256, 0, stream>>>(h0, agg, root1, w1, b1, h1);

    // layer 2
    k_gather<64><<<(NSEG * 16 + 255) / 256, 256, 0, stream>>>(start, cur, esrc, h1, agg);
    k_combine_t<64><<<(NN + 127) / 128, 256, 0, stream>>>(h1, agg, root2, w2, b2, h2);

    // pooling + classifier
    k_pool<<<NG, 256, 0, stream>>>(h2, batch, pool);
    k_final<<<(NG * 10 + 255) / 256, 256, 0, stream>>>(pool, cw, cb, out);
}